// Round 13
// baseline (1252.226 us; speedup 1.0000x reference)
//
#include <hip/hip_runtime.h>

// ConvexPolytopeManifold: dual-PGD QP projection. B=4096, n=512, m=1024.
// Round 30: B-DIRECT fragments from repacked Q (r27 base, 893.96us best).
// Evidence: two byte-cut nulls (r25 operands, r29 K-split -18% LDS reads)
// -> the ~2000cy/phase floor is not byte-bound. Untested: removing the
// B-staging pipeline itself. Q is fixed for 59 dispatches, 2MB, L2-resident.
// Change (BD=1 path, used when W==Q, K=1024): repack Q into fragment-major
// Qp[rnb][kt][kk][quad][l15][8] (one-time ~1us kernel). Each wave's B
// fragment = ONE coalesced 1KB global_load_dwordx4 (lane offset = lane*16B
// -- fixes r13's 2KB-strided gather disaster). B prefetched 1 tile ahead
// into ping-pong named register sets bfrA/bfrB (rule #20: constant idx).
// As staging shrinks to 1 GLDS/thread; LDS/CU/phase 176KB -> 80KB.
// vmcnt: issue {stage(kt+2)[1], Bload(kt+1)[4]} then vmcnt(5) == exactly
// those 5 newest in flight (in-order retire); tail vmcnt(4) at KT-2 (Bload
// only issued), vmcnt(0) at KT-1. Verified for KT=16 incl. prologue
// (6 outstanding -> 11 -> drain to 5 = stage(2)+Bload(1)).
// MFMA order identical to r27 -> bit-identical output (absmax 0.046875).
// BD=0 path (EPI0/1/5/6) = r27 verbatim (72KB LDS, 3 GLDS staging).
// Prediction: iter 13.5 -> 10.5-12us, total ~770-840us. If >=860: the
// floor is latency/barrier-structural -> declare plateau.
//
// math:
//   Q = A@A^T; y = x+u; c = y@A^T - b
//   lam1 = step*relu(c); 49x lam = relu(lam - 0.01*(lam@Q - c))
//   active = (c - lam@Q >= -TOL)
//   masked = (u@A^T) * active; lam1 = step*relu(masked)
//   9x lam = relu(lam - 0.01*(lam@Q - masked)) * active
//   out = u - lam@A

#define TOLV 1e-5f
#define STEPV 0.01f

typedef __attribute__((ext_vector_type(8))) _Float16 half8;
typedef __attribute__((ext_vector_type(4))) float floatx4;
typedef unsigned short ushort_t;
typedef __attribute__((ext_vector_type(8))) unsigned short ushort8v;

#define GLDS(gptr, lptr) \
    __builtin_amdgcn_global_load_lds( \
        (const __attribute__((address_space(1))) void*)(gptr), \
        (__attribute__((address_space(3))) void*)(lptr), 16, 0, 0)

__device__ inline ushort_t f2h(float f) {
    union { _Float16 h; ushort_t u; } c; c.h = (_Float16)f;   // RNE
    return c.u;
}
__device__ inline float h2f(ushort_t u) {
    union { ushort_t u; _Float16 h; } c; c.u = u;
    return (float)c.h;
}

__global__ void addcast_kernel(const float* __restrict__ x, const float* __restrict__ u,
                               ushort_t* __restrict__ yh, ushort_t* __restrict__ uh, int n) {
    int idx = (blockIdx.x * blockDim.x + threadIdx.x) * 4;
    if (idx < n) {
        float4 xv = *(const float4*)(x + idx);
        float4 uv = *(const float4*)(u + idx);
        ushort4 yo, uo;
        yo.x = f2h(xv.x + uv.x); yo.y = f2h(xv.y + uv.y);
        yo.z = f2h(xv.z + uv.z); yo.w = f2h(xv.w + uv.w);
        uo.x = f2h(uv.x); uo.y = f2h(uv.y); uo.z = f2h(uv.z); uo.w = f2h(uv.w);
        *(ushort4*)(yh + idx) = yo;
        *(ushort4*)(uh + idx) = uo;
    }
}

__global__ void cvt_h_kernel(const float* __restrict__ src, ushort_t* __restrict__ dst, int n) {
    int idx = (blockIdx.x * blockDim.x + threadIdx.x) * 4;
    if (idx < n) {
        float4 v = *(const float4*)(src + idx);
        ushort4 o;
        o.x = f2h(v.x); o.y = f2h(v.y); o.z = f2h(v.z); o.w = f2h(v.w);
        *(ushort4*)(dst + idx) = o;
    }
}

__global__ void transpose_cast_kernel(const float* __restrict__ A, ushort_t* __restrict__ AT,
                                      int m, int n) {
    __shared__ float t[32][33];
    int bx = blockIdx.x * 32;
    int by = blockIdx.y * 32;
    int tx = threadIdx.x & 31, ty = threadIdx.x >> 5;   // 32 x 8
#pragma unroll
    for (int i = 0; i < 32; i += 8)
        t[ty + i][tx] = A[(size_t)(by + ty + i) * n + bx + tx];
    __syncthreads();
#pragma unroll
    for (int i = 0; i < 32; i += 8)
        AT[(size_t)(bx + ty + i) * m + by + tx] = f2h(t[tx][ty + i]);
}

// Repack Q [m][K] fp16 -> Qp[rnb][kt][kk][quad][l15][8] fragment-major.
// One thread per half8. row = rnb*16+l15, k = kt*64+kk*32+quad*8.
__global__ void repack_q_kernel(const ushort_t* __restrict__ Q, ushort_t* __restrict__ Qp,
                                int m, int K) {
    int idx = blockIdx.x * blockDim.x + threadIdx.x;   // m*K/8 threads
    int cpr = K >> 3;                                  // half8 chunks per row
    int row = idx / cpr;
    int c = idx % cpr;
    if (row >= m) return;
    int kt = c >> 3, rem = c & 7, kk = rem >> 2, quad = rem & 3;
    int KT = K >> 6;
    size_t dst = ((((size_t)(row >> 4) * KT + kt) * 2 + kk) * 4 + quad) * 128 + (row & 15) * 8;
    *(ushort8v*)(Qp + dst) = *(const ushort8v*)(Q + (size_t)row * K + c * 8);
}

// ---------------- fp16 MFMA GEMM, 64x128, 8 waves, 1-barrier ----------------
// C = X @ W^T. X=[M,K] fp16. 512 thr = 8 waves, wave tile 32x32 (2Mx4N grid).
// BD=0: W=[N,K] fp16 staged to LDS (r27 verbatim: 3-buffer, 3 GLDS/thread).
// BD=1: W=Qp fragment-major; B via coalesced VMEM prefetch, As-only staging.
// Epilogue: acc -> LDS Cs (f32, stride 132) -> thread-linear coalesced I/O.
// EPI: 0 Q:      lamOut = fp16(v)
//      1 c+lam1: cv=v-bvec[col]; cFout=cv; cHout=f2h(cv); lamOut=f2h(step*relu(cv))
//      2 iter:   nv=relu(h2f(lamIn) - step*(v - h2f(cH))); lamOut=f2h(nv)
//      3 iter*act
//      4 act:    actOut = (cF - v >= -TOL) ? 1 : 0  (fp16)
//      5 masked+lam1: mv=v*act; cHout=f2h(mv); lamOut=f2h(step*relu(mv))
//      6 final:  outF = uin - v
template<int EPI, int BD>
__global__ __launch_bounds__(512, 4)
void mfma_g(const ushort_t* __restrict__ X, const ushort_t* __restrict__ W,
            const ushort_t* __restrict__ lamIn, const float* __restrict__ cF,
            const ushort_t* __restrict__ cH, const ushort_t* __restrict__ actb,
            ushort_t* __restrict__ lamOut, float* __restrict__ cFout,
            ushort_t* __restrict__ cHout, ushort_t* __restrict__ actOut,
            const float* __restrict__ uin, float* __restrict__ outF,
            const float* __restrict__ bvec,
            int M, int N, int K) {
    // BD=0: As[3][4096] + Bs[3][8192] = 36864 shorts (72KB).
    // BD=1: max(As 3x4096=12288, Cs 16896) = 16896 shorts (33.8KB).
    __shared__ short SMEM[BD ? 16896 : (3 * 64 * 64 + 3 * 128 * 64)];

    const int tid = threadIdx.x;
    const int w = tid >> 6;              // 0..7
    const int lane = tid & 63;

    const int nbm = M >> 6;
    const int spx = nbm >> 3;
    const int xcd = blockIdx.x & 7;
    const int loc = blockIdx.x >> 3;
    const int bm = (xcd * spx + (loc % spx)) << 6;
    const int bn = (loc / spx) << 7;

    const int wm = (w & 1) * 32;         // 2 wave-rows along M
    const int wn = (w >> 1) * 32;        // 4 wave-cols along N
    const int quad = lane >> 4;
    const int l15 = lane & 15;

    const int ldr = lane >> 3;
    const int csw = ((lane & 7) ^ ldr) * 8;

    const ushort_t* Xb = X + (size_t)bm * K + csw;

    floatx4 acc[2][2] = {};
    const int KT = K >> 6;

    short* const AsBase = SMEM;                           // 3 x 4096 shorts

    if (BD == 0) {
        short* const BsBase = SMEM + 3 * 64 * 64;         // 3 x 8192 shorts
        const ushort_t* Wb = W + (size_t)bn * K + csw;

        auto STAGE = [&](int kt, int bi) {
            const int ko = kt << 6;
            GLDS(Xb + (size_t)(w * 8 + ldr) * K + ko, AsBase + bi * 4096 + (w * 8) * 64);
#pragma unroll
            for (int t = 0; t < 2; ++t)
                GLDS(Wb + (size_t)(w * 16 + t * 8 + ldr) * K + ko,
                     BsBase + bi * 8192 + (w * 16 + t * 8) * 64);
        };

        STAGE(0, 0);
        STAGE(1, 1);

        int cur = 0;
        for (int kt = 0; kt < KT; ++kt) {
            if (kt + 1 < KT) {
                asm volatile("s_waitcnt vmcnt(3)" ::: "memory");
            } else {
                asm volatile("s_waitcnt vmcnt(0)" ::: "memory");
            }
            __builtin_amdgcn_s_barrier();
            if (kt + 2 < KT) {
                int nb = cur + 2; if (nb >= 3) nb -= 3;
                STAGE(kt + 2, nb);
            }

            __builtin_amdgcn_s_setprio(1);
#pragma unroll
            for (int kk = 0; kk < 2; ++kk) {
                const int sw = ((kk * 4 + quad) ^ (l15 & 7)) * 8;
                half8 af[2], bfr[2];
#pragma unroll
                for (int i = 0; i < 2; ++i)
                    af[i] = *(const half8*)(AsBase + cur * 4096 + (wm + i * 16 + l15) * 64 + sw);
#pragma unroll
                for (int i = 0; i < 2; ++i)
                    bfr[i] = *(const half8*)(BsBase + cur * 8192 + (wn + i * 16 + l15) * 64 + sw);
#pragma unroll
                for (int mt = 0; mt < 2; ++mt)
#pragma unroll
                    for (int nt = 0; nt < 2; ++nt)
                        acc[mt][nt] = __builtin_amdgcn_mfma_f32_16x16x32_f16(
                            af[mt], bfr[nt], acc[mt][nt], 0, 0, 0);
            }
            __builtin_amdgcn_s_setprio(0);
            ++cur; if (cur >= 3) cur -= 3;
        }
    } else {
        // BD==1: B fragments direct from Qp[rnb][kt][kk][quad][l15][8].
        // Per (i,kk): 1KB coalesced load at base + lane*8 halves.
        const size_t rnb0 = (size_t)((bn + wn) >> 4);
        const ushort_t* Qbase = W + rnb0 * ((size_t)KT * 1024) + lane * 8;

        auto BADDR = [&](int kt, int kk, int i) -> const half8* {
            return (const half8*)(Qbase + (size_t)i * KT * 1024 + kt * 1024 + kk * 512);
        };

        auto STAGE1 = [&](int kt, int bi) {
            GLDS(Xb + (size_t)(w * 8 + ldr) * K + (kt << 6), AsBase + bi * 4096 + (w * 8) * 64);
        };

        half8 bfrA[4], bfrB[4];   // [kk*2+i], constant indices only

        // prologue: stage(0), stage(1), Bload(0)->bfrA   (6 outstanding)
        STAGE1(0, 0);
        STAGE1(1, 1);
#pragma unroll
        for (int kk = 0; kk < 2; ++kk)
#pragma unroll
            for (int i = 0; i < 2; ++i)
                bfrA[kk * 2 + i] = *BADDR(0, kk, i);

        int cur = 0;
#pragma unroll 2
        for (int kt = 0; kt < KT; ++kt) {
            const bool evn = (kt & 1) == 0;
            // issue stage(kt+2) and Bload(kt+1) into the spare register set
            if (kt + 2 < KT) {
                int nb = cur + 2; if (nb >= 3) nb -= 3;
                STAGE1(kt + 2, nb);
            }
            if (kt + 1 < KT) {
                if (evn) {
#pragma unroll
                    for (int kk = 0; kk < 2; ++kk)
#pragma unroll
                        for (int i = 0; i < 2; ++i)
                            bfrB[kk * 2 + i] = *BADDR(kt + 1, kk, i);
                } else {
#pragma unroll
                    for (int kk = 0; kk < 2; ++kk)
#pragma unroll
                        for (int i = 0; i < 2; ++i)
                            bfrA[kk * 2 + i] = *BADDR(kt + 1, kk, i);
                }
            }
            // counted wait: keep only this iter's issues in flight
            if (kt + 2 < KT) {
                asm volatile("s_waitcnt vmcnt(5)" ::: "memory");
            } else if (kt + 1 < KT) {
                asm volatile("s_waitcnt vmcnt(4)" ::: "memory");
            } else {
                asm volatile("s_waitcnt vmcnt(0)" ::: "memory");
            }
            __builtin_amdgcn_s_barrier();      // As[cur] valid; no readers of
                                               // As[(cur+2)%3] remain (r26 arg)

            __builtin_amdgcn_s_setprio(1);
#pragma unroll
            for (int kk = 0; kk < 2; ++kk) {
                const int sw = ((kk * 4 + quad) ^ (l15 & 7)) * 8;
                half8 af[2];
#pragma unroll
                for (int i = 0; i < 2; ++i)
                    af[i] = *(const half8*)(AsBase + cur * 4096 + (wm + i * 16 + l15) * 64 + sw);
#pragma unroll
                for (int mt = 0; mt < 2; ++mt)
#pragma unroll
                    for (int nt = 0; nt < 2; ++nt)
                        acc[mt][nt] = __builtin_amdgcn_mfma_f32_16x16x32_f16(
                            af[mt], evn ? bfrA[kk * 2 + nt] : bfrB[kk * 2 + nt],
                            acc[mt][nt], 0, 0, 0);
            }
            __builtin_amdgcn_s_setprio(0);
            ++cur; if (cur >= 3) cur -= 3;
        }
    }

    // ---- epilogue: acc -> LDS Cs (f32, stride 132) -> thread-linear I/O ----
    __syncthreads();                           // all waves done with As/Bs
    float* Cs = (float*)SMEM;                  // 64 x 132 f32 = 33792 B

#pragma unroll
    for (int mt = 0; mt < 2; ++mt)
#pragma unroll
        for (int nt = 0; nt < 2; ++nt)
#pragma unroll
            for (int r = 0; r < 4; ++r) {
                int rl = wm + mt * 16 + quad * 4 + r;
                int cl = wn + nt * 16 + l15;
                Cs[rl * 132 + cl] = acc[mt][nt][r];
            }
    __syncthreads();

    const int rl = tid >> 3;
    const int c0 = (tid & 7) * 16;
    const int grow = bm + rl;
    const int gcol = bn + c0;
    const size_t gidx = (size_t)grow * N + gcol;

    float v[16];
#pragma unroll
    for (int j = 0; j < 4; ++j)
        *(floatx4*)(v + 4 * j) = *(const floatx4*)(Cs + rl * 132 + c0 + 4 * j);

    if (EPI == 0) {
        ushort_t hv[16];
#pragma unroll
        for (int j = 0; j < 16; ++j) hv[j] = f2h(v[j]);
        *(ushort8v*)(lamOut + gidx) = *(ushort8v*)hv;
        *(ushort8v*)(lamOut + gidx + 8) = *(ushort8v*)(hv + 8);
    } else if (EPI == 1) {
        float bv[16];
#pragma unroll
        for (int j = 0; j < 4; ++j)
            *(floatx4*)(bv + 4 * j) = *(const floatx4*)(bvec + gcol + 4 * j);
        ushort_t ch[16], lo[16];
        float cf[16];
#pragma unroll
        for (int j = 0; j < 16; ++j) {
            float cv = v[j] - bv[j];
            cf[j] = cv;
            ch[j] = f2h(cv);
            lo[j] = f2h(STEPV * fmaxf(cv, 0.0f));
        }
#pragma unroll
        for (int j = 0; j < 4; ++j)
            *(floatx4*)(cFout + gidx + 4 * j) = *(floatx4*)(cf + 4 * j);
        *(ushort8v*)(cHout + gidx) = *(ushort8v*)ch;
        *(ushort8v*)(cHout + gidx + 8) = *(ushort8v*)(ch + 8);
        *(ushort8v*)(lamOut + gidx) = *(ushort8v*)lo;
        *(ushort8v*)(lamOut + gidx + 8) = *(ushort8v*)(lo + 8);
    } else if (EPI == 2 || EPI == 3) {
        ushort_t li[16], ch[16], ab[16], lo[16];
        *(ushort8v*)li = *(const ushort8v*)(lamIn + gidx);
        *(ushort8v*)(li + 8) = *(const ushort8v*)(lamIn + gidx + 8);
        *(ushort8v*)ch = *(const ushort8v*)(cH + gidx);
        *(ushort8v*)(ch + 8) = *(const ushort8v*)(cH + gidx + 8);
        if (EPI == 3) {
            *(ushort8v*)ab = *(const ushort8v*)(actb + gidx);
            *(ushort8v*)(ab + 8) = *(const ushort8v*)(actb + gidx + 8);
        }
#pragma unroll
        for (int j = 0; j < 16; ++j) {
            float nv = fmaxf(fmaf(-STEPV, v[j] - h2f(ch[j]), h2f(li[j])), 0.0f);
            if (EPI == 3) nv *= h2f(ab[j]);
            lo[j] = f2h(nv);
        }
        *(ushort8v*)(lamOut + gidx) = *(ushort8v*)lo;
        *(ushort8v*)(lamOut + gidx + 8) = *(ushort8v*)(lo + 8);
    } else if (EPI == 4) {
        float cf[16];
#pragma unroll
        for (int j = 0; j < 4; ++j)
            *(floatx4*)(cf + 4 * j) = *(const floatx4*)(cF + gidx + 4 * j);
        ushort_t ao[16];
#pragma unroll
        for (int j = 0; j < 16; ++j)
            ao[j] = (cf[j] - v[j] >= -TOLV) ? (ushort_t)0x3C00 : (ushort_t)0;
        *(ushort8v*)(actOut + gidx) = *(ushort8v*)ao;
        *(ushort8v*)(actOut + gidx + 8) = *(ushort8v*)(ao + 8);
    } else if (EPI == 5) {
        ushort_t ab[16], ch[16], lo[16];
        *(ushort8v*)ab = *(const ushort8v*)(actb + gidx);
        *(ushort8v*)(ab + 8) = *(const ushort8v*)(actb + gidx + 8);
#pragma unroll
        for (int j = 0; j < 16; ++j) {
            float mv = v[j] * h2f(ab[j]);
            ch[j] = f2h(mv);
            lo[j] = f2h(STEPV * fmaxf(mv, 0.0f));
        }
        *(ushort8v*)(cHout + gidx) = *(ushort8v*)ch;
        *(ushort8v*)(cHout + gidx + 8) = *(ushort8v*)(ch + 8);
        *(ushort8v*)(lamOut + gidx) = *(ushort8v*)lo;
        *(ushort8v*)(lamOut + gidx + 8) = *(ushort8v*)(lo + 8);
    } else if (EPI == 6) {
        float uv[16], ov[16];
#pragma unroll
        for (int j = 0; j < 4; ++j)
            *(floatx4*)(uv + 4 * j) = *(const floatx4*)(uin + gidx + 4 * j);
#pragma unroll
        for (int j = 0; j < 16; ++j) ov[j] = uv[j] - v[j];
#pragma unroll
        for (int j = 0; j < 4; ++j)
            *(floatx4*)(outF + gidx + 4 * j) = *(floatx4*)(ov + 4 * j);
    }
}

static inline int grid1d(int M, int N) { return (M >> 6) * (N >> 7); }

extern "C" void kernel_launch(void* const* d_in, const int* in_sizes, int n_in,
                              void* d_out, int out_size, void* d_ws, size_t ws_size,
                              hipStream_t stream) {
    const float* x = (const float*)d_in[0];  // [B,n]
    const float* u = (const float*)d_in[1];  // [B,n]
    const float* A = (const float*)d_in[2];  // [m,n]
    const float* b = (const float*)d_in[3];  // [m]
    float* out = (float*)d_out;              // [B,n]

    const int B = 4096, n = 512, m = 1024;
    const size_t Bm = (size_t)B * m;
    const size_t Bn = (size_t)B * n;

    ushort_t* A_h   = (ushort_t*)d_ws;             // [m,n]
    ushort_t* AT_h  = A_h + (size_t)m * n;         // [n,m]
    ushort_t* y_h   = AT_h + (size_t)n * m;        // [B,n]
    ushort_t* u_h   = y_h + Bn;                    // [B,n]
    ushort_t* Q_h   = u_h + Bn;                    // [m,m]
    ushort_t* lamA  = Q_h + (size_t)m * m;         // [B,m] fp16
    ushort_t* lamB  = lamA + Bm;                   // [B,m] fp16
    ushort_t* act   = lamB + Bm;                   // [B,m] fp16 0/1
    ushort_t* cHbuf = act + Bm;                    // [B,m] fp16 (c, then masked)
    float* cFbuf = (float*)(cHbuf + Bm);           // [B,m] f32 (c, for act test)
    ushort_t* Qp    = (ushort_t*)(cFbuf + Bm);     // [m*m] fp16 fragment-major

    dim3 blk(512);

    addcast_kernel<<<(int)(Bn / 4 + 255) / 256, 256, 0, stream>>>(x, u, y_h, u_h, (int)Bn);
    cvt_h_kernel<<<(m * n / 4 + 255) / 256, 256, 0, stream>>>(A, A_h, m * n);
    transpose_cast_kernel<<<dim3(n / 32, m / 32), dim3(256), 0, stream>>>(A, AT_h, m, n);

    // Q = fp16(A @ A^T)
    mfma_g<0, 0><<<grid1d(m, m), blk, 0, stream>>>(
        A_h, A_h, nullptr, nullptr, nullptr, nullptr,
        Q_h, nullptr, nullptr, nullptr, nullptr, nullptr, nullptr, m, m, n);

    // repack Q -> fragment-major Qp
    repack_q_kernel<<<(m * m / 8 + 255) / 256, 256, 0, stream>>>(Q_h, Qp, m, m);

    // c = y@A^T - b (cF fp32 + cH fp16); lamA = fp16(lam1 = step*relu(c))
    mfma_g<1, 0><<<grid1d(B, m), blk, 0, stream>>>(
        y_h, A_h, nullptr, nullptr, nullptr, nullptr,
        lamA, cFbuf, cHbuf, nullptr, nullptr, nullptr, b, B, m, n);

    // phase 1: 49 more iterations (lam fp16 ping-pong), B-direct from Qp
    ushort_t* lin = lamA; ushort_t* lout = lamB;
    for (int it = 0; it < 49; ++it) {
        mfma_g<2, 1><<<grid1d(B, m), blk, 0, stream>>>(
            lin, Qp, lin, nullptr, cHbuf, nullptr,
            lout, nullptr, nullptr, nullptr, nullptr, nullptr, nullptr, B, m, m);
        ushort_t* t = lin; lin = lout; lout = t;
    }

    // active = (c - lam50@Q >= -TOL), B-direct
    mfma_g<4, 1><<<grid1d(B, m), blk, 0, stream>>>(
        lin, Qp, nullptr, cFbuf, nullptr, nullptr,
        nullptr, nullptr, nullptr, act, nullptr, nullptr, nullptr, B, m, m);

    // masked = (u@A^T)*active -> cHbuf; lamA = fp16(lam1 = step*relu(masked))
    mfma_g<5, 0><<<grid1d(B, m), blk, 0, stream>>>(
        u_h, A_h, nullptr, nullptr, nullptr, act,
        lamA, nullptr, cHbuf, nullptr, nullptr, nullptr, nullptr, B, m, n);

    // phase 2: 9 more iterations, B-direct
    lin = lamA; lout = lamB;
    for (int it = 0; it < 9; ++it) {
        mfma_g<3, 1><<<grid1d(B, m), blk, 0, stream>>>(
            lin, Qp, lin, nullptr, cHbuf, act,
            lout, nullptr, nullptr, nullptr, nullptr, nullptr, nullptr, B, m, m);
        ushort_t* t = lin; lin = lout; lout = t;
    }

    // out = u - lam @ A
    mfma_g<6, 0><<<grid1d(B, n), blk, 0, stream>>>(
        lin, AT_h, nullptr, nullptr, nullptr, nullptr,
        nullptr, nullptr, nullptr, nullptr, u, out, nullptr, B, n, m);
}

// Round 14
// 1027.832 us; speedup vs baseline: 1.2183x; 1.2183x over previous
//
#include <hip/hip_runtime.h>

// ConvexPolytopeManifold: dual-PGD QP projection. B=4096, n=512, m=1024.
// Round 31: REVERT r30 (B-direct: 1252us, VMEM path loses to LDS staging)
// -> back to r27 structure (893.96us best). Consolidation round:
//  (1) EPI7 = fused EPI4+EPI5: two sequential K-loops (lam50@Q K=1024,
//      u@A^T K=512) sharing LDS buffers, one inter-loop barrier (r26
//      hazard argument); epilogue computes act -> masked -> lam1
//      in-register. Saves one dispatch's fixed cost. act still written.
//  (2) T14 prefetch of EPI2/3 epilogue operands (issued before prologue
//      STAGEs; first vmcnt(3) drains them -> no added stalls, in-order).
// Evidence ledger: epilogue-coalesce -157, barriers -74, occupancy -30,
// drain -15; byte-cuts null x2 (r25,r29); staging-removal bad (r30);
// 1 blk/CU bad x2 (r18/r21). Phase floor ~2000cy is sync/latency
// structural; 8-phase template needs 256^2 tiles N=1024 can't feed.
// Prediction: ~875-890us, absmax 0.046875 (bit-identical MFMA order).
//
// math:
//   Q = A@A^T; y = x+u; c = y@A^T - b
//   lam1 = step*relu(c); 49x lam = relu(lam - 0.01*(lam@Q - c))
//   active = (c - lam@Q >= -TOL)
//   masked = (u@A^T) * active; lam1 = step*relu(masked)
//   9x lam = relu(lam - 0.01*(lam@Q - masked)) * active
//   out = u - lam@A

#define TOLV 1e-5f
#define STEPV 0.01f

typedef __attribute__((ext_vector_type(8))) _Float16 half8;
typedef __attribute__((ext_vector_type(4))) float floatx4;
typedef unsigned short ushort_t;
typedef __attribute__((ext_vector_type(8))) unsigned short ushort8v;

#define GLDS(gptr, lptr) \
    __builtin_amdgcn_global_load_lds( \
        (const __attribute__((address_space(1))) void*)(gptr), \
        (__attribute__((address_space(3))) void*)(lptr), 16, 0, 0)

__device__ inline ushort_t f2h(float f) {
    union { _Float16 h; ushort_t u; } c; c.h = (_Float16)f;   // RNE
    return c.u;
}
__device__ inline float h2f(ushort_t u) {
    union { ushort_t u; _Float16 h; } c; c.u = u;
    return (float)c.h;
}

__global__ void addcast_kernel(const float* __restrict__ x, const float* __restrict__ u,
                               ushort_t* __restrict__ yh, ushort_t* __restrict__ uh, int n) {
    int idx = (blockIdx.x * blockDim.x + threadIdx.x) * 4;
    if (idx < n) {
        float4 xv = *(const float4*)(x + idx);
        float4 uv = *(const float4*)(u + idx);
        ushort4 yo, uo;
        yo.x = f2h(xv.x + uv.x); yo.y = f2h(xv.y + uv.y);
        yo.z = f2h(xv.z + uv.z); yo.w = f2h(xv.w + uv.w);
        uo.x = f2h(uv.x); uo.y = f2h(uv.y); uo.z = f2h(uv.z); uo.w = f2h(uv.w);
        *(ushort4*)(yh + idx) = yo;
        *(ushort4*)(uh + idx) = uo;
    }
}

__global__ void cvt_h_kernel(const float* __restrict__ src, ushort_t* __restrict__ dst, int n) {
    int idx = (blockIdx.x * blockDim.x + threadIdx.x) * 4;
    if (idx < n) {
        float4 v = *(const float4*)(src + idx);
        ushort4 o;
        o.x = f2h(v.x); o.y = f2h(v.y); o.z = f2h(v.z); o.w = f2h(v.w);
        *(ushort4*)(dst + idx) = o;
    }
}

__global__ void transpose_cast_kernel(const float* __restrict__ A, ushort_t* __restrict__ AT,
                                      int m, int n) {
    __shared__ float t[32][33];
    int bx = blockIdx.x * 32;
    int by = blockIdx.y * 32;
    int tx = threadIdx.x & 31, ty = threadIdx.x >> 5;   // 32 x 8
#pragma unroll
    for (int i = 0; i < 32; i += 8)
        t[ty + i][tx] = A[(size_t)(by + ty + i) * n + bx + tx];
    __syncthreads();
#pragma unroll
    for (int i = 0; i < 32; i += 8)
        AT[(size_t)(bx + ty + i) * m + by + tx] = f2h(t[tx][ty + i]);
}

// ---------------- fp16 MFMA GEMM, 64x128, 8 waves, 1-barrier 3-buffer --------
// C = X @ W^T. X=[M,K] fp16, W=[N,K] fp16. 512 thr = 8 waves.
// Tile 64Mx128N, BK=64, wave tile 32x32 (2x2 of 16x16x32 f16), waves 2Mx4N.
// XOR-swizzled LDS; XCD-aware 1D grid. 3 GLDS/thread/tile.
// K-loop: wait vmcnt -> barrier -> STAGE(kt+2) -> ds_read+MFMA (r27).
// Epilogue: acc -> LDS (f32, stride 132) -> thread-linear coalesced I/O.
// EPI: 0 Q:      lamOut = fp16(v)
//      1 c+lam1: cv=v-bvec[col]; cFout=cv; cHout=f2h(cv); lamOut=f2h(step*relu(cv))
//      2 iter:   nv=relu(h2f(lamIn) - step*(v - h2f(cH))); lamOut=f2h(nv)
//      3 iter*act
//      6 final:  outF = uin - v
//      7 fused act+masked: v1=X@W^T (K); v2=X2@W2^T (K/2) with X2=lamIn,
//        W2=cH; act=(cF-v1>=-TOL); mv=v2*act; actOut=act; cHout=f2h(mv);
//        lamOut=f2h(step*relu(mv))
template<int EPI>
__global__ __launch_bounds__(512, 4)
void mfma_g(const ushort_t* __restrict__ X, const ushort_t* __restrict__ W,
            const ushort_t* __restrict__ lamIn, const float* __restrict__ cF,
            const ushort_t* __restrict__ cH, const ushort_t* __restrict__ actb,
            ushort_t* __restrict__ lamOut, float* __restrict__ cFout,
            ushort_t* __restrict__ cHout, ushort_t* __restrict__ actOut,
            const float* __restrict__ uin, float* __restrict__ outF,
            const float* __restrict__ bvec,
            int M, int N, int K) {
    // As[3][4096] + Bs[3][8192] shorts; epilogue aliases front as [64][132] f32.
    __shared__ short SMEM[3 * 64 * 64 + 3 * 128 * 64];   // 72 KB, 2 blk/CU

    const int tid = threadIdx.x;
    const int w = tid >> 6;              // 0..7
    const int lane = tid & 63;

    const int nbm = M >> 6;
    const int spx = nbm >> 3;
    const int xcd = blockIdx.x & 7;
    const int loc = blockIdx.x >> 3;
    const int bm = (xcd * spx + (loc % spx)) << 6;
    const int bn = (loc / spx) << 7;

    const int wm = (w & 1) * 32;         // 2 wave-rows along M
    const int wn = (w >> 1) * 32;        // 4 wave-cols along N
    const int quad = lane >> 4;
    const int l15 = lane & 15;

    const int ldr = lane >> 3;
    const int csw = ((lane & 7) ^ ldr) * 8;

    // epilogue linear mapping (computed early for T14 prefetch)
    const int rl = tid >> 3;
    const int c0 = (tid & 7) * 16;
    const int grow = bm + rl;
    const int gcol = bn + c0;
    const size_t gidx = (size_t)grow * N + gcol;

    // T14: issue EPI2/3 epilogue operand loads BEFORE the staging pipeline.
    // In-order retire: these are the oldest VMEM ops; the first vmcnt(3)
    // drains them without extra stalls. Data sits in VGPRs until epilogue.
    ushort_t li[16], chv[16], abv[16];
    if (EPI == 2 || EPI == 3) {
        *(ushort8v*)li = *(const ushort8v*)(lamIn + gidx);
        *(ushort8v*)(li + 8) = *(const ushort8v*)(lamIn + gidx + 8);
        *(ushort8v*)chv = *(const ushort8v*)(cH + gidx);
        *(ushort8v*)(chv + 8) = *(const ushort8v*)(cH + gidx + 8);
        if (EPI == 3) {
            *(ushort8v*)abv = *(const ushort8v*)(actb + gidx);
            *(ushort8v*)(abv + 8) = *(const ushort8v*)(actb + gidx + 8);
        }
    }

    floatx4 acc[2][2] = {};
    const int KT = K >> 6;

    short* const AsBase = SMEM;                 // 3 x 4096 shorts
    short* const BsBase = SMEM + 3 * 64 * 64;   // 3 x 8192 shorts

    // r27 K-loop over (XbL, WbL) with row stride KL, KTL tiles, into accL.
    auto RUNLOOP = [&](const ushort_t* XbL, const ushort_t* WbL, int KL, int KTL,
                       floatx4 (&accL)[2][2]) {
        auto STAGE = [&](int kt, int bi) {
            const int ko = kt << 6;
            GLDS(XbL + (size_t)(w * 8 + ldr) * KL + ko, AsBase + bi * 4096 + (w * 8) * 64);
#pragma unroll
            for (int t = 0; t < 2; ++t)
                GLDS(WbL + (size_t)(w * 16 + t * 8 + ldr) * KL + ko,
                     BsBase + bi * 8192 + (w * 16 + t * 8) * 64);
        };

        STAGE(0, 0);
        STAGE(1, 1);

        int cur = 0;
        for (int kt = 0; kt < KTL; ++kt) {
            if (kt + 1 < KTL) {
                asm volatile("s_waitcnt vmcnt(3)" ::: "memory");
            } else {
                asm volatile("s_waitcnt vmcnt(0)" ::: "memory");
            }
            __builtin_amdgcn_s_barrier();      // buf[cur] valid; no readers of
                                               // buf[(cur+2)%3] remain (r26 arg)
            if (kt + 2 < KTL) {
                int nb = cur + 2; if (nb >= 3) nb -= 3;
                STAGE(kt + 2, nb);             // overlaps this tile's compute
            }

            __builtin_amdgcn_s_setprio(1);
#pragma unroll
            for (int kk = 0; kk < 2; ++kk) {
                const int sw = ((kk * 4 + quad) ^ (l15 & 7)) * 8;
                half8 af[2], bfr[2];
#pragma unroll
                for (int i = 0; i < 2; ++i)
                    af[i] = *(const half8*)(AsBase + cur * 4096 + (wm + i * 16 + l15) * 64 + sw);
#pragma unroll
                for (int i = 0; i < 2; ++i)
                    bfr[i] = *(const half8*)(BsBase + cur * 8192 + (wn + i * 16 + l15) * 64 + sw);
#pragma unroll
                for (int mt = 0; mt < 2; ++mt)
#pragma unroll
                    for (int nt = 0; nt < 2; ++nt)
                        accL[mt][nt] = __builtin_amdgcn_mfma_f32_16x16x32_f16(
                            af[mt], bfr[nt], accL[mt][nt], 0, 0, 0);
            }
            __builtin_amdgcn_s_setprio(0);
            ++cur; if (cur >= 3) cur -= 3;
        }
    };

    const ushort_t* Xb = X + (size_t)bm * K + csw;
    const ushort_t* Wb = W + (size_t)bn * K + csw;
    RUNLOOP(Xb, Wb, K, KT, acc);

    floatx4 acc2[2][2] = {};
    if (EPI == 7) {
        // loop2: v2 = X2 @ W2^T, X2=lamIn(u_h), W2=cH(A_h), K2=K/2.
        __builtin_amdgcn_s_barrier();          // loop1 readers of buf0 done
        const int K2 = K >> 1;
        const ushort_t* Xb2 = lamIn + (size_t)bm * K2 + csw;
        const ushort_t* Wb2 = cH + (size_t)bn * K2 + csw;
        RUNLOOP(Xb2, Wb2, K2, K2 >> 6, acc2);
    }

    // ---- epilogue: acc -> LDS Cs (f32, stride 132) -> thread-linear I/O ----
    __syncthreads();                           // all waves done reading As/Bs
    float* Cs = (float*)SMEM;                  // 64 x 132 f32 = 33792 B

#pragma unroll
    for (int mt = 0; mt < 2; ++mt)
#pragma unroll
        for (int nt = 0; nt < 2; ++nt)
#pragma unroll
            for (int r = 0; r < 4; ++r) {
                int rlw = wm + mt * 16 + quad * 4 + r;
                int cl = wn + nt * 16 + l15;
                Cs[rlw * 132 + cl] = acc[mt][nt][r];
            }
    __syncthreads();

    float v[16];
#pragma unroll
    for (int j = 0; j < 4; ++j)
        *(floatx4*)(v + 4 * j) = *(const floatx4*)(Cs + rl * 132 + c0 + 4 * j);

    float v2[16];
    if (EPI == 7) {
        __syncthreads();                       // all v reads done before overwrite
#pragma unroll
        for (int mt = 0; mt < 2; ++mt)
#pragma unroll
            for (int nt = 0; nt < 2; ++nt)
#pragma unroll
                for (int r = 0; r < 4; ++r) {
                    int rlw = wm + mt * 16 + quad * 4 + r;
                    int cl = wn + nt * 16 + l15;
                    Cs[rlw * 132 + cl] = acc2[mt][nt][r];
                }
        __syncthreads();
#pragma unroll
        for (int j = 0; j < 4; ++j)
            *(floatx4*)(v2 + 4 * j) = *(const floatx4*)(Cs + rl * 132 + c0 + 4 * j);
    }

    if (EPI == 0) {
        ushort_t hv[16];
#pragma unroll
        for (int j = 0; j < 16; ++j) hv[j] = f2h(v[j]);
        *(ushort8v*)(lamOut + gidx) = *(ushort8v*)hv;
        *(ushort8v*)(lamOut + gidx + 8) = *(ushort8v*)(hv + 8);
    } else if (EPI == 1) {
        float bv[16];
#pragma unroll
        for (int j = 0; j < 4; ++j)
            *(floatx4*)(bv + 4 * j) = *(const floatx4*)(bvec + gcol + 4 * j);
        ushort_t ch[16], lo[16];
        float cf[16];
#pragma unroll
        for (int j = 0; j < 16; ++j) {
            float cv = v[j] - bv[j];
            cf[j] = cv;
            ch[j] = f2h(cv);
            lo[j] = f2h(STEPV * fmaxf(cv, 0.0f));
        }
#pragma unroll
        for (int j = 0; j < 4; ++j)
            *(floatx4*)(cFout + gidx + 4 * j) = *(floatx4*)(cf + 4 * j);
        *(ushort8v*)(cHout + gidx) = *(ushort8v*)ch;
        *(ushort8v*)(cHout + gidx + 8) = *(ushort8v*)(ch + 8);
        *(ushort8v*)(lamOut + gidx) = *(ushort8v*)lo;
        *(ushort8v*)(lamOut + gidx + 8) = *(ushort8v*)(lo + 8);
    } else if (EPI == 2 || EPI == 3) {
        ushort_t lo[16];
#pragma unroll
        for (int j = 0; j < 16; ++j) {
            float nv = fmaxf(fmaf(-STEPV, v[j] - h2f(chv[j]), h2f(li[j])), 0.0f);
            if (EPI == 3) nv *= h2f(abv[j]);
            lo[j] = f2h(nv);
        }
        *(ushort8v*)(lamOut + gidx) = *(ushort8v*)lo;
        *(ushort8v*)(lamOut + gidx + 8) = *(ushort8v*)(lo + 8);
    } else if (EPI == 6) {
        float uv[16], ov[16];
#pragma unroll
        for (int j = 0; j < 4; ++j)
            *(floatx4*)(uv + 4 * j) = *(const floatx4*)(uin + gidx + 4 * j);
#pragma unroll
        for (int j = 0; j < 16; ++j) ov[j] = uv[j] - v[j];
#pragma unroll
        for (int j = 0; j < 4; ++j)
            *(floatx4*)(outF + gidx + 4 * j) = *(floatx4*)(ov + 4 * j);
    } else if (EPI == 7) {
        float cf[16];
#pragma unroll
        for (int j = 0; j < 4; ++j)
            *(floatx4*)(cf + 4 * j) = *(const floatx4*)(cF + gidx + 4 * j);
        ushort_t ao[16], ch[16], lo[16];
#pragma unroll
        for (int j = 0; j < 16; ++j) {
            bool on = (cf[j] - v[j] >= -TOLV);
            ao[j] = on ? (ushort_t)0x3C00 : (ushort_t)0;
            float mv = on ? v2[j] : 0.0f;      // v2 * act, act in {1,0}
            ch[j] = f2h(mv);
            lo[j] = f2h(STEPV * fmaxf(mv, 0.0f));
        }
        *(ushort8v*)(actOut + gidx) = *(ushort8v*)ao;
        *(ushort8v*)(actOut + gidx + 8) = *(ushort8v*)(ao + 8);
        *(ushort8v*)(cHout + gidx) = *(ushort8v*)ch;
        *(ushort8v*)(cHout + gidx + 8) = *(ushort8v*)(ch + 8);
        *(ushort8v*)(lamOut + gidx) = *(ushort8v*)lo;
        *(ushort8v*)(lamOut + gidx + 8) = *(ushort8v*)(lo + 8);
    }
}

static inline int grid1d(int M, int N) { return (M >> 6) * (N >> 7); }

extern "C" void kernel_launch(void* const* d_in, const int* in_sizes, int n_in,
                              void* d_out, int out_size, void* d_ws, size_t ws_size,
                              hipStream_t stream) {
    const float* x = (const float*)d_in[0];  // [B,n]
    const float* u = (const float*)d_in[1];  // [B,n]
    const float* A = (const float*)d_in[2];  // [m,n]
    const float* b = (const float*)d_in[3];  // [m]
    float* out = (float*)d_out;              // [B,n]

    const int B = 4096, n = 512, m = 1024;
    const size_t Bm = (size_t)B * m;
    const size_t Bn = (size_t)B * n;

    ushort_t* A_h   = (ushort_t*)d_ws;             // [m,n]
    ushort_t* AT_h  = A_h + (size_t)m * n;         // [n,m]
    ushort_t* y_h   = AT_h + (size_t)n * m;        // [B,n]
    ushort_t* u_h   = y_h + Bn;                    // [B,n]
    ushort_t* Q_h   = u_h + Bn;                    // [m,m]
    ushort_t* lamA  = Q_h + (size_t)m * m;         // [B,m] fp16
    ushort_t* lamB  = lamA + Bm;                   // [B,m] fp16
    ushort_t* act   = lamB + Bm;                   // [B,m] fp16 0/1
    ushort_t* cHbuf = act + Bm;                    // [B,m] fp16 (c, then masked)
    float* cFbuf = (float*)(cHbuf + Bm);           // [B,m] f32 (c, for act test)

    dim3 blk(512);

    addcast_kernel<<<(int)(Bn / 4 + 255) / 256, 256, 0, stream>>>(x, u, y_h, u_h, (int)Bn);
    cvt_h_kernel<<<(m * n / 4 + 255) / 256, 256, 0, stream>>>(A, A_h, m * n);
    transpose_cast_kernel<<<dim3(n / 32, m / 32), dim3(256), 0, stream>>>(A, AT_h, m, n);

    // Q = fp16(A @ A^T)
    mfma_g<0><<<grid1d(m, m), blk, 0, stream>>>(
        A_h, A_h, nullptr, nullptr, nullptr, nullptr,
        Q_h, nullptr, nullptr, nullptr, nullptr, nullptr, nullptr, m, m, n);

    // c = y@A^T - b (cF fp32 + cH fp16); lamA = fp16(lam1 = step*relu(c))
    mfma_g<1><<<grid1d(B, m), blk, 0, stream>>>(
        y_h, A_h, nullptr, nullptr, nullptr, nullptr,
        lamA, cFbuf, cHbuf, nullptr, nullptr, nullptr, b, B, m, n);

    // phase 1: 49 more iterations (lam fp16 ping-pong)
    ushort_t* lin = lamA; ushort_t* lout = lamB;
    for (int it = 0; it < 49; ++it) {
        mfma_g<2><<<grid1d(B, m), blk, 0, stream>>>(
            lin, Q_h, lin, nullptr, cHbuf, nullptr,
            lout, nullptr, nullptr, nullptr, nullptr, nullptr, nullptr, B, m, m);
        ushort_t* t = lin; lin = lout; lout = t;
    }

    // FUSED: active = (c - lam50@Q >= -TOL); masked = (u@A^T)*active -> cHbuf;
    // lamA = fp16(lam1 = step*relu(masked)); act written for phase 2.
    mfma_g<7><<<grid1d(B, m), blk, 0, stream>>>(
        lin, Q_h, u_h, cFbuf, A_h, nullptr,
        lamA, nullptr, cHbuf, act, nullptr, nullptr, nullptr, B, m, m);

    // phase 2: 9 more iterations
    lin = lamA; lout = lamB;
    for (int it = 0; it < 9; ++it) {
        mfma_g<3><<<grid1d(B, m), blk, 0, stream>>>(
            lin, Q_h, lin, nullptr, cHbuf, act,
            lout, nullptr, nullptr, nullptr, nullptr, nullptr, nullptr, B, m, m);
        ushort_t* t = lin; lin = lout; lout = t;
    }

    // out = u - lam @ A
    mfma_g<6><<<grid1d(B, n), blk, 0, stream>>>(
        lin, AT_h, nullptr, nullptr, nullptr, nullptr,
        nullptr, nullptr, nullptr, nullptr, u, out, nullptr, B, n, m);
}

// Round 15
// 948.716 us; speedup vs baseline: 1.3199x; 1.0834x over previous
//
#include <hip/hip_runtime.h>

// ConvexPolytopeManifold: dual-PGD QP projection. B=4096, n=512, m=1024.
// Round 32: UNBUNDLE r31. r31 (+134us) bundled two all-instantiation
// changes with the fusion: T14 operand prefetch (12 VGPRs pinned across
// K-loop; r25 already showed epilogue loads are hidden -> pure cost) and
// a RUNLOOP lambda refactor of the hot loop. This round: r27 VERBATIM
// for all EPIs (inline loop, no prefetch, epilogue loads in-branch) +
// ONLY the EPI7 fusion, isolated via if constexpr so other
// instantiations compile byte-identical to the 894us build.
// EPI7 (proven correct in r31, absmax 0.046875): two sequential K-loops
// (lam50@Q K=1024; u@A^T K=512) sharing LDS, one inter-loop barrier
// (r26 hazard argument); epilogue act->masked->lam1 in-register ==
// bit-identical to EPI4+EPI5. Saves one dispatch's fixed cost.
// Prediction: ~884-890us, absmax 0.046875. If EPI7 alone regresses ->
// drop fusion, r27 = final plateau.
//
// math:
//   Q = A@A^T; y = x+u; c = y@A^T - b
//   lam1 = step*relu(c); 49x lam = relu(lam - 0.01*(lam@Q - c))
//   active = (c - lam@Q >= -TOL)
//   masked = (u@A^T) * active; lam1 = step*relu(masked)
//   9x lam = relu(lam - 0.01*(lam@Q - masked)) * active
//   out = u - lam@A

#define TOLV 1e-5f
#define STEPV 0.01f

typedef __attribute__((ext_vector_type(8))) _Float16 half8;
typedef __attribute__((ext_vector_type(4))) float floatx4;
typedef unsigned short ushort_t;
typedef __attribute__((ext_vector_type(8))) unsigned short ushort8v;

#define GLDS(gptr, lptr) \
    __builtin_amdgcn_global_load_lds( \
        (const __attribute__((address_space(1))) void*)(gptr), \
        (__attribute__((address_space(3))) void*)(lptr), 16, 0, 0)

__device__ inline ushort_t f2h(float f) {
    union { _Float16 h; ushort_t u; } c; c.h = (_Float16)f;   // RNE
    return c.u;
}
__device__ inline float h2f(ushort_t u) {
    union { ushort_t u; _Float16 h; } c; c.u = u;
    return (float)c.h;
}

__global__ void addcast_kernel(const float* __restrict__ x, const float* __restrict__ u,
                               ushort_t* __restrict__ yh, ushort_t* __restrict__ uh, int n) {
    int idx = (blockIdx.x * blockDim.x + threadIdx.x) * 4;
    if (idx < n) {
        float4 xv = *(const float4*)(x + idx);
        float4 uv = *(const float4*)(u + idx);
        ushort4 yo, uo;
        yo.x = f2h(xv.x + uv.x); yo.y = f2h(xv.y + uv.y);
        yo.z = f2h(xv.z + uv.z); yo.w = f2h(xv.w + uv.w);
        uo.x = f2h(uv.x); uo.y = f2h(uv.y); uo.z = f2h(uv.z); uo.w = f2h(uv.w);
        *(ushort4*)(yh + idx) = yo;
        *(ushort4*)(uh + idx) = uo;
    }
}

__global__ void cvt_h_kernel(const float* __restrict__ src, ushort_t* __restrict__ dst, int n) {
    int idx = (blockIdx.x * blockDim.x + threadIdx.x) * 4;
    if (idx < n) {
        float4 v = *(const float4*)(src + idx);
        ushort4 o;
        o.x = f2h(v.x); o.y = f2h(v.y); o.z = f2h(v.z); o.w = f2h(v.w);
        *(ushort4*)(dst + idx) = o;
    }
}

__global__ void transpose_cast_kernel(const float* __restrict__ A, ushort_t* __restrict__ AT,
                                      int m, int n) {
    __shared__ float t[32][33];
    int bx = blockIdx.x * 32;
    int by = blockIdx.y * 32;
    int tx = threadIdx.x & 31, ty = threadIdx.x >> 5;   // 32 x 8
#pragma unroll
    for (int i = 0; i < 32; i += 8)
        t[ty + i][tx] = A[(size_t)(by + ty + i) * n + bx + tx];
    __syncthreads();
#pragma unroll
    for (int i = 0; i < 32; i += 8)
        AT[(size_t)(bx + ty + i) * m + by + tx] = f2h(t[tx][ty + i]);
}

// ---------------- fp16 MFMA GEMM, 64x128, 8 waves, 1-barrier 3-buffer --------
// C = X @ W^T. X=[M,K] fp16, W=[N,K] fp16. 512 thr = 8 waves.
// Tile 64Mx128N, BK=64, wave tile 32x32 (2x2 of 16x16x32 f16), waves 2Mx4N.
// XOR-swizzled LDS; XCD-aware 1D grid. 3 GLDS/thread/tile.
// K-loop: wait vmcnt -> barrier -> STAGE(kt+2) -> ds_read+MFMA (r27).
// Epilogue: acc -> LDS (f32, stride 132) -> thread-linear coalesced I/O.
// EPI: 0 Q:      lamOut = fp16(v)
//      1 c+lam1: cv=v-bvec[col]; cFout=cv; cHout=f2h(cv); lamOut=f2h(step*relu(cv))
//      2 iter:   nv=relu(h2f(lamIn) - step*(v - h2f(cH))); lamOut=f2h(nv)
//      3 iter*act
//      4 act:    actOut = (cF - v >= -TOL) ? 1 : 0  (fp16)
//      5 masked+lam1: mv=v*act; cHout=f2h(mv); lamOut=f2h(step*relu(mv))
//      6 final:  outF = uin - v
//      7 fused 4+5: v=lam50@Q (K); v2=u@A^T (K/2, X2=lamIn, W2=cH);
//        act=(cF-v>=-TOL); mv=act?v2:0; actOut, cHout=f2h(mv),
//        lamOut=f2h(step*relu(mv))
template<int EPI>
__global__ __launch_bounds__(512, 4)
void mfma_g(const ushort_t* __restrict__ X, const ushort_t* __restrict__ W,
            const ushort_t* __restrict__ lamIn, const float* __restrict__ cF,
            const ushort_t* __restrict__ cH, const ushort_t* __restrict__ actb,
            ushort_t* __restrict__ lamOut, float* __restrict__ cFout,
            ushort_t* __restrict__ cHout, ushort_t* __restrict__ actOut,
            const float* __restrict__ uin, float* __restrict__ outF,
            const float* __restrict__ bvec,
            int M, int N, int K) {
    // As[3][4096] + Bs[3][8192] shorts; epilogue aliases front as [64][132] f32.
    __shared__ short SMEM[3 * 64 * 64 + 3 * 128 * 64];   // 72 KB, 2 blk/CU

    const int tid = threadIdx.x;
    const int w = tid >> 6;              // 0..7
    const int lane = tid & 63;

    const int nbm = M >> 6;
    const int spx = nbm >> 3;
    const int xcd = blockIdx.x & 7;
    const int loc = blockIdx.x >> 3;
    const int bm = (xcd * spx + (loc % spx)) << 6;
    const int bn = (loc / spx) << 7;

    const int wm = (w & 1) * 32;         // 2 wave-rows along M
    const int wn = (w >> 1) * 32;        // 4 wave-cols along N
    const int quad = lane >> 4;
    const int l15 = lane & 15;

    const int ldr = lane >> 3;
    const int csw = ((lane & 7) ^ ldr) * 8;

    const ushort_t* Xb = X + (size_t)bm * K + csw;
    const ushort_t* Wb = W + (size_t)bn * K + csw;

    floatx4 acc[2][2] = {};
    floatx4 acc2[2][2] = {};

    const int KT = K >> 6;

    short* const AsBase = SMEM;                 // 3 x 4096 shorts
    short* const BsBase = SMEM + 3 * 64 * 64;   // 3 x 8192 shorts

    // stage tile kt into buffer bi: 1 GLDS (As) + 2 GLDS (Bs) per thread
    auto STAGE = [&](int kt, int bi) {
        const int ko = kt << 6;
        GLDS(Xb + (size_t)(w * 8 + ldr) * K + ko, AsBase + bi * 4096 + (w * 8) * 64);
#pragma unroll
        for (int t = 0; t < 2; ++t)
            GLDS(Wb + (size_t)(w * 16 + t * 8 + ldr) * K + ko,
                 BsBase + bi * 8192 + (w * 16 + t * 8) * 64);
    };

    // prologue: stage tiles 0 and 1 (6 loads in flight)
    STAGE(0, 0);
    STAGE(1, 1);

    int cur = 0;
    for (int kt = 0; kt < KT; ++kt) {
        // per-wave wait: own stage(kt) loads landed; stage(kt+1) stays in flight
        if (kt + 1 < KT) {
            asm volatile("s_waitcnt vmcnt(3)" ::: "memory");
        } else {
            asm volatile("s_waitcnt vmcnt(0)" ::: "memory");
        }
        __builtin_amdgcn_s_barrier();          // buf[cur] valid for all waves;
                                               // no wave still reads buf[(cur+2)%3]
        if (kt + 2 < KT) {
            int nb = cur + 2; if (nb >= 3) nb -= 3;
            STAGE(kt + 2, nb);                 // overlaps this tile's compute
        }

        __builtin_amdgcn_s_setprio(1);
#pragma unroll
        for (int kk = 0; kk < 2; ++kk) {
            const int sw = ((kk * 4 + quad) ^ (l15 & 7)) * 8;
            half8 af[2], bfr[2];
#pragma unroll
            for (int i = 0; i < 2; ++i)
                af[i] = *(const half8*)(AsBase + cur * 4096 + (wm + i * 16 + l15) * 64 + sw);
#pragma unroll
            for (int i = 0; i < 2; ++i)
                bfr[i] = *(const half8*)(BsBase + cur * 8192 + (wn + i * 16 + l15) * 64 + sw);
#pragma unroll
            for (int mt = 0; mt < 2; ++mt)
#pragma unroll
                for (int nt = 0; nt < 2; ++nt)
                    acc[mt][nt] = __builtin_amdgcn_mfma_f32_16x16x32_f16(
                        af[mt], bfr[nt], acc[mt][nt], 0, 0, 0);
        }
        __builtin_amdgcn_s_setprio(0);
        ++cur; if (cur >= 3) cur -= 3;
    }

    // ---- EPI7 only: second K-loop v2 = lamIn @ cH^T with K2 = K/2 ----
    if constexpr (EPI == 7) {
        const int K2 = K >> 1;
        const int KT2 = K2 >> 6;
        const ushort_t* Xb2 = lamIn + (size_t)bm * K2 + csw;
        const ushort_t* Wb2 = cH + (size_t)bn * K2 + csw;

        __builtin_amdgcn_s_barrier();          // loop1's last-buffer reads done

        auto STAGE2 = [&](int kt, int bi) {
            const int ko = kt << 6;
            GLDS(Xb2 + (size_t)(w * 8 + ldr) * K2 + ko, AsBase + bi * 4096 + (w * 8) * 64);
#pragma unroll
            for (int t = 0; t < 2; ++t)
                GLDS(Wb2 + (size_t)(w * 16 + t * 8 + ldr) * K2 + ko,
                     BsBase + bi * 8192 + (w * 16 + t * 8) * 64);
        };

        STAGE2(0, 0);
        STAGE2(1, 1);

        int cur2 = 0;
        for (int kt = 0; kt < KT2; ++kt) {
            if (kt + 1 < KT2) {
                asm volatile("s_waitcnt vmcnt(3)" ::: "memory");
            } else {
                asm volatile("s_waitcnt vmcnt(0)" ::: "memory");
            }
            __builtin_amdgcn_s_barrier();
            if (kt + 2 < KT2) {
                int nb = cur2 + 2; if (nb >= 3) nb -= 3;
                STAGE2(kt + 2, nb);
            }

            __builtin_amdgcn_s_setprio(1);
#pragma unroll
            for (int kk = 0; kk < 2; ++kk) {
                const int sw = ((kk * 4 + quad) ^ (l15 & 7)) * 8;
                half8 af[2], bfr[2];
#pragma unroll
                for (int i = 0; i < 2; ++i)
                    af[i] = *(const half8*)(AsBase + cur2 * 4096 + (wm + i * 16 + l15) * 64 + sw);
#pragma unroll
                for (int i = 0; i < 2; ++i)
                    bfr[i] = *(const half8*)(BsBase + cur2 * 8192 + (wn + i * 16 + l15) * 64 + sw);
#pragma unroll
                for (int mt = 0; mt < 2; ++mt)
#pragma unroll
                    for (int nt = 0; nt < 2; ++nt)
                        acc2[mt][nt] = __builtin_amdgcn_mfma_f32_16x16x32_f16(
                            af[mt], bfr[nt], acc2[mt][nt], 0, 0, 0);
            }
            __builtin_amdgcn_s_setprio(0);
            ++cur2; if (cur2 >= 3) cur2 -= 3;
        }
    }

    // ---- epilogue: acc -> LDS (f32, stride 132) -> thread-linear coalesced ----
    __syncthreads();                           // all waves done reading As/Bs
    float* Cs = (float*)SMEM;                  // 64 x 132 f32 = 33792 B

    // write acc in C/D layout: row = quad*4+r, col = lane&15 per 16x16 tile
#pragma unroll
    for (int mt = 0; mt < 2; ++mt)
#pragma unroll
        for (int nt = 0; nt < 2; ++nt)
#pragma unroll
            for (int r = 0; r < 4; ++r) {
                int rl = wm + mt * 16 + quad * 4 + r;
                int cl = wn + nt * 16 + l15;
                Cs[rl * 132 + cl] = acc[mt][nt][r];
            }
    __syncthreads();

    // linear phase: thread t -> row t>>3 (0..63), col chunk (t&7)*16
    const int rl = tid >> 3;
    const int c0 = (tid & 7) * 16;
    const int grow = bm + rl;
    const int gcol = bn + c0;
    const size_t gidx = (size_t)grow * N + gcol;

    float v[16];
#pragma unroll
    for (int j = 0; j < 4; ++j)
        *(floatx4*)(v + 4 * j) = *(const floatx4*)(Cs + rl * 132 + c0 + 4 * j);

    float v2[16];
    if constexpr (EPI == 7) {
        __syncthreads();                       // all v reads done before overwrite
#pragma unroll
        for (int mt = 0; mt < 2; ++mt)
#pragma unroll
            for (int nt = 0; nt < 2; ++nt)
#pragma unroll
                for (int r = 0; r < 4; ++r) {
                    int rlw = wm + mt * 16 + quad * 4 + r;
                    int cl = wn + nt * 16 + l15;
                    Cs[rlw * 132 + cl] = acc2[mt][nt][r];
                }
        __syncthreads();
#pragma unroll
        for (int j = 0; j < 4; ++j)
            *(floatx4*)(v2 + 4 * j) = *(const floatx4*)(Cs + rl * 132 + c0 + 4 * j);
    }

    if (EPI == 0) {
        ushort_t hv[16];
#pragma unroll
        for (int j = 0; j < 16; ++j) hv[j] = f2h(v[j]);
        *(ushort8v*)(lamOut + gidx) = *(ushort8v*)hv;
        *(ushort8v*)(lamOut + gidx + 8) = *(ushort8v*)(hv + 8);
    } else if (EPI == 1) {
        float bv[16];
#pragma unroll
        for (int j = 0; j < 4; ++j)
            *(floatx4*)(bv + 4 * j) = *(const floatx4*)(bvec + gcol + 4 * j);
        ushort_t ch[16], lo[16];
        float cf[16];
#pragma unroll
        for (int j = 0; j < 16; ++j) {
            float cv = v[j] - bv[j];
            cf[j] = cv;
            ch[j] = f2h(cv);
            lo[j] = f2h(STEPV * fmaxf(cv, 0.0f));
        }
#pragma unroll
        for (int j = 0; j < 4; ++j)
            *(floatx4*)(cFout + gidx + 4 * j) = *(floatx4*)(cf + 4 * j);
        *(ushort8v*)(cHout + gidx) = *(ushort8v*)ch;
        *(ushort8v*)(cHout + gidx + 8) = *(ushort8v*)(ch + 8);
        *(ushort8v*)(lamOut + gidx) = *(ushort8v*)lo;
        *(ushort8v*)(lamOut + gidx + 8) = *(ushort8v*)(lo + 8);
    } else if (EPI == 2 || EPI == 3) {
        ushort_t li[16], ch[16], ab[16], lo[16];
        *(ushort8v*)li = *(const ushort8v*)(lamIn + gidx);
        *(ushort8v*)(li + 8) = *(const ushort8v*)(lamIn + gidx + 8);
        *(ushort8v*)ch = *(const ushort8v*)(cH + gidx);
        *(ushort8v*)(ch + 8) = *(const ushort8v*)(cH + gidx + 8);
        if (EPI == 3) {
            *(ushort8v*)ab = *(const ushort8v*)(actb + gidx);
            *(ushort8v*)(ab + 8) = *(const ushort8v*)(actb + gidx + 8);
        }
#pragma unroll
        for (int j = 0; j < 16; ++j) {
            float nv = fmaxf(fmaf(-STEPV, v[j] - h2f(ch[j]), h2f(li[j])), 0.0f);
            if (EPI == 3) nv *= h2f(ab[j]);
            lo[j] = f2h(nv);
        }
        *(ushort8v*)(lamOut + gidx) = *(ushort8v*)lo;
        *(ushort8v*)(lamOut + gidx + 8) = *(ushort8v*)(lo + 8);
    } else if (EPI == 4) {
        float cf[16];
#pragma unroll
        for (int j = 0; j < 4; ++j)
            *(floatx4*)(cf + 4 * j) = *(const floatx4*)(cF + gidx + 4 * j);
        ushort_t ao[16];
#pragma unroll
        for (int j = 0; j < 16; ++j)
            ao[j] = (cf[j] - v[j] >= -TOLV) ? (ushort_t)0x3C00 : (ushort_t)0;
        *(ushort8v*)(actOut + gidx) = *(ushort8v*)ao;
        *(ushort8v*)(actOut + gidx + 8) = *(ushort8v*)(ao + 8);
    } else if (EPI == 5) {
        ushort_t ab[16], ch[16], lo[16];
        *(ushort8v*)ab = *(const ushort8v*)(actb + gidx);
        *(ushort8v*)(ab + 8) = *(const ushort8v*)(actb + gidx + 8);
#pragma unroll
        for (int j = 0; j < 16; ++j) {
            float mv = v[j] * h2f(ab[j]);
            ch[j] = f2h(mv);
            lo[j] = f2h(STEPV * fmaxf(mv, 0.0f));
        }
        *(ushort8v*)(cHout + gidx) = *(ushort8v*)ch;
        *(ushort8v*)(cHout + gidx + 8) = *(ushort8v*)(ch + 8);
        *(ushort8v*)(lamOut + gidx) = *(ushort8v*)lo;
        *(ushort8v*)(lamOut + gidx + 8) = *(ushort8v*)(lo + 8);
    } else if (EPI == 6) {
        float uv[16], ov[16];
#pragma unroll
        for (int j = 0; j < 4; ++j)
            *(floatx4*)(uv + 4 * j) = *(const floatx4*)(uin + gidx + 4 * j);
#pragma unroll
        for (int j = 0; j < 16; ++j) ov[j] = uv[j] - v[j];
#pragma unroll
        for (int j = 0; j < 4; ++j)
            *(floatx4*)(outF + gidx + 4 * j) = *(floatx4*)(ov + 4 * j);
    } else if (EPI == 7) {
        float cf[16];
#pragma unroll
        for (int j = 0; j < 4; ++j)
            *(floatx4*)(cf + 4 * j) = *(const floatx4*)(cF + gidx + 4 * j);
        ushort_t ao[16], ch[16], lo[16];
#pragma unroll
        for (int j = 0; j < 16; ++j) {
            bool on = (cf[j] - v[j] >= -TOLV);
            ao[j] = on ? (ushort_t)0x3C00 : (ushort_t)0;
            float mv = on ? v2[j] : 0.0f;      // v2 * act, act in {1,0}
            ch[j] = f2h(mv);
            lo[j] = f2h(STEPV * fmaxf(mv, 0.0f));
        }
        *(ushort8v*)(actOut + gidx) = *(ushort8v*)ao;
        *(ushort8v*)(actOut + gidx + 8) = *(ushort8v*)(ao + 8);
        *(ushort8v*)(cHout + gidx) = *(ushort8v*)ch;
        *(ushort8v*)(cHout + gidx + 8) = *(ushort8v*)(ch + 8);
        *(ushort8v*)(lamOut + gidx) = *(ushort8v*)lo;
        *(ushort8v*)(lamOut + gidx + 8) = *(ushort8v*)(lo + 8);
    }
}

static inline int grid1d(int M, int N) { return (M >> 6) * (N >> 7); }

extern "C" void kernel_launch(void* const* d_in, const int* in_sizes, int n_in,
                              void* d_out, int out_size, void* d_ws, size_t ws_size,
                              hipStream_t stream) {
    const float* x = (const float*)d_in[0];  // [B,n]
    const float* u = (const float*)d_in[1];  // [B,n]
    const float* A = (const float*)d_in[2];  // [m,n]
    const float* b = (const float*)d_in[3];  // [m]
    float* out = (float*)d_out;              // [B,n]

    const int B = 4096, n = 512, m = 1024;
    const size_t Bm = (size_t)B * m;
    const size_t Bn = (size_t)B * n;

    ushort_t* A_h   = (ushort_t*)d_ws;             // [m,n]
    ushort_t* AT_h  = A_h + (size_t)m * n;         // [n,m]
    ushort_t* y_h   = AT_h + (size_t)n * m;        // [B,n]
    ushort_t* u_h   = y_h + Bn;                    // [B,n]
    ushort_t* Q_h   = u_h + Bn;                    // [m,m]
    ushort_t* lamA  = Q_h + (size_t)m * m;         // [B,m] fp16
    ushort_t* lamB  = lamA + Bm;                   // [B,m] fp16
    ushort_t* act   = lamB + Bm;                   // [B,m] fp16 0/1
    ushort_t* cHbuf = act + Bm;                    // [B,m] fp16 (c, then masked)
    float* cFbuf = (float*)(cHbuf + Bm);           // [B,m] f32 (c, for act test)

    dim3 blk(512);

    addcast_kernel<<<(int)(Bn / 4 + 255) / 256, 256, 0, stream>>>(x, u, y_h, u_h, (int)Bn);
    cvt_h_kernel<<<(m * n / 4 + 255) / 256, 256, 0, stream>>>(A, A_h, m * n);
    transpose_cast_kernel<<<dim3(n / 32, m / 32), dim3(256), 0, stream>>>(A, AT_h, m, n);

    // Q = fp16(A @ A^T)
    mfma_g<0><<<grid1d(m, m), blk, 0, stream>>>(
        A_h, A_h, nullptr, nullptr, nullptr, nullptr,
        Q_h, nullptr, nullptr, nullptr, nullptr, nullptr, nullptr, m, m, n);

    // c = y@A^T - b (cF fp32 + cH fp16); lamA = fp16(lam1 = step*relu(c))
    mfma_g<1><<<grid1d(B, m), blk, 0, stream>>>(
        y_h, A_h, nullptr, nullptr, nullptr, nullptr,
        lamA, cFbuf, cHbuf, nullptr, nullptr, nullptr, b, B, m, n);

    // phase 1: 49 more iterations (lam fp16 ping-pong)
    ushort_t* lin = lamA; ushort_t* lout = lamB;
    for (int it = 0; it < 49; ++it) {
        mfma_g<2><<<grid1d(B, m), blk, 0, stream>>>(
            lin, Q_h, lin, nullptr, cHbuf, nullptr,
            lout, nullptr, nullptr, nullptr, nullptr, nullptr, nullptr, B, m, m);
        ushort_t* t = lin; lin = lout; lout = t;
    }

    // FUSED: active = (c - lam50@Q >= -TOL); masked = (u@A^T)*active -> cHbuf;
    // lamA = fp16(lam1 = step*relu(masked)); act written for phase 2.
    mfma_g<7><<<grid1d(B, m), blk, 0, stream>>>(
        lin, Q_h, u_h, cFbuf, A_h, nullptr,
        lamA, nullptr, cHbuf, act, nullptr, nullptr, nullptr, B, m, m);

    // phase 2: 9 more iterations
    lin = lamA; lout = lamB;
    for (int it = 0; it < 9; ++it) {
        mfma_g<3><<<grid1d(B, m), blk, 0, stream>>>(
            lin, Q_h, lin, nullptr, cHbuf, act,
            lout, nullptr, nullptr, nullptr, nullptr, nullptr, nullptr, B, m, m);
        ushort_t* t = lin; lin = lout; lout = t;
    }

    // out = u - lam @ A
    mfma_g<6><<<grid1d(B, n), blk, 0, stream>>>(
        lin, AT_h, nullptr, nullptr, nullptr, nullptr,
        nullptr, nullptr, nullptr, nullptr, u, out, nullptr, B, n, m);
}